// Round 18
// baseline (1699.470 us; speedup 1.0000x reference)
//
#include <hip/hip_runtime.h>

// LSTM BS=512, T=2048, IN=64, HS=128.  Single fused persistent kernel.
// 256 blocks x 2 rows, 8 waves; bf16 chunk GEMM (Z=x@W+b) from LDS-staged x
// (T14); scan = i8 MFMA U*h (mfma_i32_16x16x64_i8); lane-local epilogue.
// R18: the two batch rows run as two STAGGERED chains (T15 double-pipeline):
// chain A (row 0, lanes 0-15) and chain B (row 1, lanes 16-31) each get their
// own 8-MFMA U*h product, offset half an iteration, so one chain's MFMA +
// ds_read latency hides under the other chain's activation chain.
// Iteration: [epiB(t-1) | mfmaA(t)] bar [epiA(t) | mfmaB(t)] bar.

#define T_STEPS 2048
#define IN_DIM 64
#define HS 128
#define NG 512
#define ROWS 2
#define NBLK 256
#define NTHR 512
#define CH 32
#define NCH (T_STEPS / CH)
#define HROW 144

typedef float f32x4 __attribute__((ext_vector_type(4)));
typedef short s16x8 __attribute__((ext_vector_type(8)));
typedef int   i32x4 __attribute__((ext_vector_type(4)));

__device__ __forceinline__ unsigned f2bf(float f) {
  unsigned u = __float_as_uint(f);
  return (u + 0x7fffu + ((u >> 16) & 1u)) >> 16;  // RNE
}
__device__ __forceinline__ float bf2f(unsigned short s) {
  return __int_as_float(((int)s) << 16);
}
__device__ __forceinline__ float rcpf(float x) { return __builtin_amdgcn_rcpf(x); }
__device__ __forceinline__ float sigm(float x) { return rcpf(1.f + __expf(-x)); }
__device__ __forceinline__ float tanhfast(float x) {
  return 1.0f - 2.0f * rcpf(__expf(2.0f * x) + 1.0f);  // exact at +-inf
}
__device__ __forceinline__ int xswz(int f) { return f ^ (((f >> 7) & 7) << 3); }

__global__ __launch_bounds__(NTHR, 1)
void lstm_fused(const float* __restrict__ X, const float* __restrict__ W,
                const float* __restrict__ U, const float* __restrict__ B,
                const float* __restrict__ LW, const float* __restrict__ LB,
                float* __restrict__ OUT) {
  __shared__ __align__(16) short Zc[CH * 128 * 8];       // 64 KB gates bf16
  __shared__ __align__(16) float Xl[4096];               // 16 KB x-tile
  __shared__ __align__(16) unsigned char HqA[HROW];      // chain A h (i8)
  __shared__ __align__(16) unsigned char HqB[HROW];      // chain B h (i8)
  __shared__ float Ys[256];
  __shared__ float Ps[8];

  const int tid  = threadIdx.x;
  const int lane = tid & 63;
  const int w    = tid >> 6;
  const int blk  = blockIdx.x;
  const int lrow = lane & 15;
  const int lg   = lane >> 4;
  const int col8 = (w * 16 + lrow) * 8;     // Zc cell offset (shorts)

  // ---- U: per-column i8 quantization (R17 verbatim) ----
  i32x4 bUq[4][2];
  float scl[4];
  s16x8 bfrW[4][2];
  float biasg[4];
#pragma unroll
  for (int n = 0; n < 4; ++n) {
    const int p = n * HS + w * 16 + lrow;
    float m = 1e-8f;
    for (int k = 0; k < HS; ++k) m = fmaxf(m, fabsf(U[k * NG + p]));
    const float rsu = 127.f / m;
    scl[n] = m / (127.f * 127.f);
#pragma unroll
    for (int kt = 0; kt < 2; ++kt) {
      int vq[4] = {0, 0, 0, 0};
      for (int j = 0; j < 16; ++j) {
        const int k = kt * 64 + (lg << 4) + j;
        int q = (int)rintf(U[k * NG + p] * rsu);
        q = q < -127 ? -127 : (q > 127 ? 127 : q);
        vq[j >> 2] |= (q & 0xff) << ((j & 3) * 8);
      }
      bUq[n][kt] = (i32x4){vq[0], vq[1], vq[2], vq[3]};
    }
#pragma unroll
    for (int kt = 0; kt < 2; ++kt)
#pragma unroll
      for (int j = 0; j < 8; ++j)
        bfrW[n][kt][j] = (short)f2bf(W[(kt * 32 + (lg << 3) + j) * NG + p]);
    biasg[n] = B[p];
  }

  // ---- x staging (T14 split, R17 verbatim) ----
  f32x4 sx0, sx1, sx2, sx3;
  auto stage_load = [&](int cc) {
    if (w < 4) {
#pragma unroll
      for (int q = 0; q < 4; ++q) {
        const int f   = w * 1024 + q * 256 + lane * 4;
        const int tlc = f >> 7;
        const int row = (f >> 6) & 1;
        const int k   = f & 63;
        const f32x4 v = *(const f32x4*)(
            X + ((long)(blk * ROWS + row) * T_STEPS + (long)cc * CH + tlc) * IN_DIM + k);
        if (q == 0) sx0 = v; else if (q == 1) sx1 = v;
        else if (q == 2) sx2 = v; else sx3 = v;
      }
    }
  };
  auto stage_write = [&]() {
    if (w < 4) {
#pragma unroll
      for (int q = 0; q < 4; ++q) {
        const int f = w * 1024 + q * 256 + lane * 4;
        const f32x4 v = (q == 0) ? sx0 : (q == 1) ? sx1 : (q == 2) ? sx2 : sx3;
        *(f32x4*)&Xl[xswz(f)] = v;
      }
    }
  };

  stage_load(0);
  stage_write();
  for (int i = tid; i < HROW; i += NTHR) { HqA[i] = 0; HqB[i] = 0; }

  const i32x4 izer = {0, 0, 0, 0};
  i32x4 afrA[2] = {izer, izer};
  i32x4 afrB[2] = {izer, izer};
  i32x4 accB[4] = {izer, izer, izer, izer};
  uint2 zuB = {0u, 0u};
  float creg = 0.f, hreg = 0.f;   // A state on lanes 0-15, B on 16-31
  __syncthreads();

#pragma unroll 1
  for (int c = 0; c < NCH; ++c) {
    // ===== chunk GEMM: Zc = x@W + bias (R17 verbatim) =====================
#pragma unroll
    for (int mt = 0; mt < 4; ++mt) {
      const int fb = mt * 1024 + (lrow >> 1) * 128 + (lrow & 1) * 64;
      const int f0 = xswz(fb + 8 * lg);
      const int f1 = xswz(fb + 32 + 8 * lg);
      const f32x4 x0 = *(const f32x4*)&Xl[f0];
      const f32x4 x1 = *(const f32x4*)&Xl[f0 + 4];
      const f32x4 x2 = *(const f32x4*)&Xl[f1];
      const f32x4 x3 = *(const f32x4*)&Xl[f1 + 4];
      s16x8 a0, a1;
#pragma unroll
      for (int j = 0; j < 4; ++j) {
        a0[j] = (short)f2bf(x0[j]); a0[4 + j] = (short)f2bf(x1[j]);
        a1[j] = (short)f2bf(x2[j]); a1[4 + j] = (short)f2bf(x3[j]);
      }
      f32x4 ac[4];
#pragma unroll
      for (int n = 0; n < 4; ++n) {
        ac[n][0] = biasg[n]; ac[n][1] = biasg[n];
        ac[n][2] = biasg[n]; ac[n][3] = biasg[n];
      }
#pragma unroll
      for (int n = 0; n < 4; ++n)
        ac[n] = __builtin_amdgcn_mfma_f32_16x16x32_bf16(a0, bfrW[n][0], ac[n], 0, 0, 0);
#pragma unroll
      for (int n = 0; n < 4; ++n)
        ac[n] = __builtin_amdgcn_mfma_f32_16x16x32_bf16(a1, bfrW[n][1], ac[n], 0, 0, 0);
      s16x8 z0, z1;
#pragma unroll
      for (int n = 0; n < 4; ++n) {
        z0[n] = (short)f2bf(ac[n][0]); z0[4 + n] = (short)f2bf(ac[n][1]);
        z1[n] = (short)f2bf(ac[n][2]); z1[4 + n] = (short)f2bf(ac[n][3]);
      }
      const int tl0 = mt * 8 + 2 * lg;
      *(s16x8*)&Zc[tl0 * 1024 + col8]       = z0;
      *(s16x8*)&Zc[(tl0 + 1) * 1024 + col8] = z1;
    }
    __syncthreads();
    stage_load((c + 1 < NCH) ? c + 1 : c);

    // ===== 32 scan iterations, two staggered chains =======================
#pragma unroll 1
    for (int tl = 0; tl < CH; ++tl) {
      const int t = c * CH + tl;
      const uint2 zu = *(const uint2*)&Zc[tl * 1024 + col8 + (lg & 1) * 4];

      // -- epilogue B for step t-1 (fills afrA ds_read latency) --
      if (t > 0 && lg == 1) {
        const float v0 = (float)accB[0][0] * scl[0] + bf2f((unsigned short)(zuB.x & 0xffff));
        const float v1 = (float)accB[1][0] * scl[1] + bf2f((unsigned short)(zuB.x >> 16));
        const float v2 = (float)accB[2][0] * scl[2] + bf2f((unsigned short)(zuB.y & 0xffff));
        const float v3 = (float)accB[3][0] * scl[3] + bf2f((unsigned short)(zuB.y >> 16));
        const float iv = sigm(v0), fv = sigm(v1);
        const float gv = tanhfast(v2), ov = sigm(v3);
        creg = fv * creg + iv * gv;
        hreg = ov * tanhfast(creg);
        HqB[w * 16 + lrow] = (unsigned char)(int)rintf(hreg * 127.f);
      }
      zuB = zu;

      // -- MFMA chain A: gates_A(t) = U * h_A(t-1) --
      i32x4 accA[4] = {izer, izer, izer, izer};
      __builtin_amdgcn_s_setprio(1);
#pragma unroll
      for (int kt = 0; kt < 2; ++kt) {
        accA[0] = __builtin_amdgcn_mfma_i32_16x16x64_i8(afrA[kt], bUq[0][kt], accA[0], 0, 0, 0);
        accA[1] = __builtin_amdgcn_mfma_i32_16x16x64_i8(afrA[kt], bUq[1][kt], accA[1], 0, 0, 0);
        accA[2] = __builtin_amdgcn_mfma_i32_16x16x64_i8(afrA[kt], bUq[2][kt], accA[2], 0, 0, 0);
        accA[3] = __builtin_amdgcn_mfma_i32_16x16x64_i8(afrA[kt], bUq[3][kt], accA[3], 0, 0, 0);
      }
      __builtin_amdgcn_s_setprio(0);
      __syncthreads();                              // barrier 1

      // afrB for B's step t (h_B(t-1), in A-row 4) -- issue read early
      if (lrow == 4) {
        afrB[0] = *(const i32x4*)&HqB[lg << 4];
        afrB[1] = *(const i32x4*)&HqB[64 + (lg << 4)];
      }

      // -- epilogue A for step t (fills afrB ds_read latency) --
      if (lg == 0) {
        const float v0 = (float)accA[0][0] * scl[0] + bf2f((unsigned short)(zu.x & 0xffff));
        const float v1 = (float)accA[1][0] * scl[1] + bf2f((unsigned short)(zu.x >> 16));
        const float v2 = (float)accA[2][0] * scl[2] + bf2f((unsigned short)(zu.y & 0xffff));
        const float v3 = (float)accA[3][0] * scl[3] + bf2f((unsigned short)(zu.y >> 16));
        const float iv = sigm(v0), fv = sigm(v1);
        const float gv = tanhfast(v2), ov = sigm(v3);
        creg = fv * creg + iv * gv;
        hreg = ov * tanhfast(creg);
        const int colc = w * 16 + lrow;
        if (t < T_STEPS - 1) {
          HqA[colc] = (unsigned char)(int)rintf(hreg * 127.f);
        } else {
          const int row = blk * ROWS;
          OUT[512 + row * HS + colc]   = hreg;
          OUT[66048 + row * HS + colc] = creg;
          Ys[colc] = LW[colc] * hreg;
        }
      }

      // -- MFMA chain B: gates_B(t) = U * h_B(t-1) --
      __builtin_amdgcn_s_setprio(1);
#pragma unroll
      for (int kt = 0; kt < 2; ++kt) {
        accB[0] = (kt == 0) ? __builtin_amdgcn_mfma_i32_16x16x64_i8(afrB[0], bUq[0][0], izer, 0, 0, 0)
                            : __builtin_amdgcn_mfma_i32_16x16x64_i8(afrB[1], bUq[0][1], accB[0], 0, 0, 0);
        accB[1] = (kt == 0) ? __builtin_amdgcn_mfma_i32_16x16x64_i8(afrB[0], bUq[1][0], izer, 0, 0, 0)
                            : __builtin_amdgcn_mfma_i32_16x16x64_i8(afrB[1], bUq[1][1], accB[1], 0, 0, 0);
        accB[2] = (kt == 0) ? __builtin_amdgcn_mfma_i32_16x16x64_i8(afrB[0], bUq[2][0], izer, 0, 0, 0)
                            : __builtin_amdgcn_mfma_i32_16x16x64_i8(afrB[1], bUq[2][1], accB[2], 0, 0, 0);
        accB[3] = (kt == 0) ? __builtin_amdgcn_mfma_i32_16x16x64_i8(afrB[0], bUq[3][0], izer, 0, 0, 0)
                            : __builtin_amdgcn_mfma_i32_16x16x64_i8(afrB[1], bUq[3][1], accB[3], 0, 0, 0);
      }
      __builtin_amdgcn_s_setprio(0);

      if (tl == 4) stage_write();
      __syncthreads();                              // barrier 2

      if (t < T_STEPS - 1 && lrow == 0) {           // afrA for A's step t+1
        afrA[0] = *(const i32x4*)&HqA[lg << 4];
        afrA[1] = *(const i32x4*)&HqA[64 + (lg << 4)];
      }
    }
  }

  // -- final epilogue B (step T-1) --
  if (lg == 1) {
    const float v0 = (float)accB[0][0] * scl[0] + bf2f((unsigned short)(zuB.x & 0xffff));
    const float v1 = (float)accB[1][0] * scl[1] + bf2f((unsigned short)(zuB.x >> 16));
    const float v2 = (float)accB[2][0] * scl[2] + bf2f((unsigned short)(zuB.y & 0xffff));
    const float v3 = (float)accB[3][0] * scl[3] + bf2f((unsigned short)(zuB.y >> 16));
    const float iv = sigm(v0), fv = sigm(v1);
    const float gv = tanhfast(v2), ov = sigm(v3);
    creg = fv * creg + iv * gv;
    hreg = ov * tanhfast(creg);
    const int colc = w * 16 + lrow;
    const int row  = blk * ROWS + 1;
    OUT[512 + row * HS + colc]   = hreg;
    OUT[66048 + row * HS + colc] = creg;
    Ys[HS + colc] = LW[colc] * hreg;
  }
  __syncthreads();

  // ---- y = h @ linear_w.T + b ----
  if (tid < 8) {
    const int r = tid >> 2, seg = tid & 3;
    float s = 0.f;
#pragma unroll 8
    for (int j = 0; j < 32; ++j) s += Ys[r * 128 + seg * 32 + j];
    Ps[tid] = s;
  }
  __syncthreads();
  if (tid < ROWS) {
    OUT[blk * ROWS + tid] = LB[0] + Ps[tid * 4] + Ps[tid * 4 + 1]
                                  + Ps[tid * 4 + 2] + Ps[tid * 4 + 3];
  }
}

extern "C" void kernel_launch(void* const* d_in, const int* in_sizes, int n_in,
                              void* d_out, int out_size, void* d_ws, size_t ws_size,
                              hipStream_t stream) {
  const float* X  = (const float*)d_in[0];
  const float* W  = (const float*)d_in[1];
  const float* U  = (const float*)d_in[2];
  const float* B  = (const float*)d_in[3];
  const float* LW = (const float*)d_in[4];
  const float* LB = (const float*)d_in[5];
  lstm_fused<<<dim3(NBLK), dim3(NTHR), 0, stream>>>(X, W, U, B, LW, LB, (float*)d_out);
}